// Round 14
// baseline (292.876 us; speedup 1.0000x reference)
//
#include <hip/hip_runtime.h>
#include <hip/hip_bf16.h>
#include <stdint.h>

#define B_  256
#define L_  256
#define S_  253
#define D_  768
#define H_  128

typedef __bf16 bf16x8 __attribute__((ext_vector_type(8)));
typedef float  f32x4  __attribute__((ext_vector_type(4)));

__device__ __forceinline__ ushort f2bf(float f) {
  union { float f; uint32_t u; } v; v.f = f;
  uint32_t r = v.u + 0x7FFFu + ((v.u >> 16) & 1u);  // RNE
  return (ushort)(r >> 16);
}

__device__ __forceinline__ uint32_t cvtpk(float lo, float hi) {
  uint32_t r;
  asm("v_cvt_pk_bf16_f32 %0, %1, %2" : "=v"(r) : "v"(lo), "v"(hi));
  return r;
}

__device__ __forceinline__ void gload16(const void* g, void* l) {
  __builtin_amdgcn_global_load_lds((const __attribute__((address_space(1))) void*)g,
                                   (__attribute__((address_space(3))) void*)l,
                                   16, 0, 0);
}

// Bank swizzle (verified R5: read conflicts -> 0). LDS rows of 32 ushort =
// 4 slots of 16 B; stored slot s at row r holds global slot s ^ ((r>>1)&3).
#define SRC_OFF(l) ((((l) & 3) ^ (((l) >> 3) & 3)) * 8)
#define RD_OFF(l)  (((((l) >> 4) ^ (((l) >> 1) & 3))) * 8)
#define PANEL128 (128 * 32)
#define PANEL256 (256 * 32 + 32)

// ---------------- k_wqb: WQ f32 -> bf16 row-copy ----------------------------
__global__ __launch_bounds__(256) void k_wqb(const float* __restrict__ WQ,
                                             ushort* __restrict__ wqb) {
  int i = blockIdx.x * 256 + threadIdx.x;   // 147456 float4s exactly
  float4 c = ((const float4*)WQ)[i];
  ushort4 o;
  o.x = f2bf(c.x); o.y = f2bf(c.y); o.z = f2bf(c.z); o.w = f2bf(c.w);
  ((ushort4*)wqb)[i] = o;
}

// ---------------- k_mtm: Mt[i][j] = scale * sum_t WK[i,t]*WQ[j,t] (MFMA) ----
__global__ __launch_bounds__(256) void k_mtm(const float* __restrict__ WK,
                                             const ushort* __restrict__ wqb,
                                             ushort* __restrict__ Mt) {
  const float scale = 0.03608439182435161f;  // 1/sqrt(768)
  __shared__ __align__(16) ushort As[2][PANEL128];
  __shared__ __align__(16) ushort Bs[2][PANEL128];
  int bm = blockIdx.x / 6, bn = blockIdx.x % 6;
  int row0 = bm * 128, col0 = bn * 128;
  int tid = threadIdx.x;
  int w = tid >> 6, l = tid & 63;
  int wr = w >> 1, wc = w & 1;
  int src_off = SRC_OFF(l);
  int rd_off  = RD_OFF(l);

  int rt = tid >> 4;
  int c4 = tid & 15;
  int h_thr = c4 >> 3;
  int cw = c4 & 7;
  const float* athr = WK + (size_t)(row0 + rt) * D_ + 4 * c4;
  int aw_base = rt * 64 + ((cw >> 1) ^ ((rt >> 1) & 3)) * 16 + (cw & 1) * 8;
  char* aw_ptr = (char*)&As[h_thr][0] + aw_base;

  f32x4 acc[4][4];
#pragma unroll
  for (int m = 0; m < 4; ++m)
#pragma unroll
    for (int n = 0; n < 4; ++n) acc[m][n] = (f32x4){0.f, 0.f, 0.f, 0.f};

  float4 ap0, ap1, ap2, ap3, ap4, ap5, ap6, ap7;
  ap0 = *(const float4*)(athr + 0 * 12288);
  ap1 = *(const float4*)(athr + 1 * 12288);
  ap2 = *(const float4*)(athr + 2 * 12288);
  ap3 = *(const float4*)(athr + 3 * 12288);
  ap4 = *(const float4*)(athr + 4 * 12288);
  ap5 = *(const float4*)(athr + 5 * 12288);
  ap6 = *(const float4*)(athr + 6 * 12288);
  ap7 = *(const float4*)(athr + 7 * 12288);

  for (int i = 0; i < 12; ++i) {
    int kt = i * 64;
    if (i) __syncthreads();
    {
      uint2 d;
      d.x = cvtpk(ap0.x, ap0.y); d.y = cvtpk(ap0.z, ap0.w);
      *(uint2*)(aw_ptr + 0 * 1024) = d;
      d.x = cvtpk(ap1.x, ap1.y); d.y = cvtpk(ap1.z, ap1.w);
      *(uint2*)(aw_ptr + 1 * 1024) = d;
      d.x = cvtpk(ap2.x, ap2.y); d.y = cvtpk(ap2.z, ap2.w);
      *(uint2*)(aw_ptr + 2 * 1024) = d;
      d.x = cvtpk(ap3.x, ap3.y); d.y = cvtpk(ap3.z, ap3.w);
      *(uint2*)(aw_ptr + 3 * 1024) = d;
      d.x = cvtpk(ap4.x, ap4.y); d.y = cvtpk(ap4.z, ap4.w);
      *(uint2*)(aw_ptr + 4 * 1024) = d;
      d.x = cvtpk(ap5.x, ap5.y); d.y = cvtpk(ap5.z, ap5.w);
      *(uint2*)(aw_ptr + 5 * 1024) = d;
      d.x = cvtpk(ap6.x, ap6.y); d.y = cvtpk(ap6.z, ap6.w);
      *(uint2*)(aw_ptr + 6 * 1024) = d;
      d.x = cvtpk(ap7.x, ap7.y); d.y = cvtpk(ap7.z, ap7.w);
      *(uint2*)(aw_ptr + 7 * 1024) = d;
    }
#pragma unroll
    for (int hh = 0; hh < 2; ++hh)
#pragma unroll
      for (int g = 0; g < 2; ++g) {
        int grp = w * 2 + g;
        int grow = grp * 16 + (l >> 2);
        const ushort* bsrc = wqb + (size_t)(col0 + grow) * D_ + kt + hh * 32 + src_off;
        gload16(bsrc, (char*)Bs[hh] + grp * 1024);
      }
    {
      int ktn = (i < 11) ? kt + 64 : kt;
      const float* an = athr + ktn;
      ap0 = *(const float4*)(an + 0 * 12288);
      ap1 = *(const float4*)(an + 1 * 12288);
      ap2 = *(const float4*)(an + 2 * 12288);
      ap3 = *(const float4*)(an + 3 * 12288);
      ap4 = *(const float4*)(an + 4 * 12288);
      ap5 = *(const float4*)(an + 5 * 12288);
      ap6 = *(const float4*)(an + 6 * 12288);
      ap7 = *(const float4*)(an + 7 * 12288);
    }
    __syncthreads();

#pragma unroll
    for (int hh = 0; hh < 2; ++hh) {
      bf16x8 af[4], bfr[4];
#pragma unroll
      for (int m = 0; m < 4; ++m)
        af[m] = *(const bf16x8*)&As[hh][(wr * 64 + m * 16 + (l & 15)) * 32 + rd_off];
#pragma unroll
      for (int n = 0; n < 4; ++n)
        bfr[n] = *(const bf16x8*)&Bs[hh][(wc * 64 + n * 16 + (l & 15)) * 32 + rd_off];
#pragma unroll
      for (int m = 0; m < 4; ++m)
#pragma unroll
        for (int n = 0; n < 4; ++n)
          acc[m][n] = __builtin_amdgcn_mfma_f32_16x16x32_bf16(af[m], bfr[n], acc[m][n], 0, 0, 0);
    }
  }

  int rbase = row0 + wr * 64;
  int cbase = col0 + wc * 64;
#pragma unroll
  for (int m = 0; m < 4; ++m)
#pragma unroll
    for (int n = 0; n < 4; ++n)
#pragma unroll
      for (int i = 0; i < 4; ++i) {
        int rr = rbase + m * 16 + (l >> 4) * 4 + i;
        int cc = cbase + n * 16 + (l & 15);
        Mt[(size_t)rr * D_ + cc] = f2bf(acc[m][n][i] * scale);
      }
}

// ---------------- k_qm: qm[r][c] = sum_k ctx[r][k] * Mt[c][k]  (bf16) -------
// R14: DOUBLE-BUFFERED (1 barrier/iter, 24->13 events), mirroring k_attn's
// R13 win. Stage kt+1 (A cvt+ds_write from regs prefetched last iter; B via
// gload_lds) into buf nxt BEFORE the 32-MFMA phase on buf cur. LDS 64 KB ->
// 2 blocks/CU, each self-overlapping.
__global__ __launch_bounds__(256) void k_qm(const float* __restrict__ ctx,
                                            const ushort* __restrict__ Mt,
                                            ushort* __restrict__ qm) {
  __shared__ __align__(16) ushort As[4][PANEL128];   // [buf*2+half]
  __shared__ __align__(16) ushort Bs[4][PANEL128];
  int bid0 = blockIdx.x;              // 0..3071
  int xcd = bid0 & 7;
  int idx = bid0 >> 3;                // 0..383
  int bm = xcd * 64 + idx / 6;        // 0..511 (bijective)
  int bn = idx % 6;
  int row0 = bm * 128, col0 = bn * 128;
  int tid = threadIdx.x;
  int w = tid >> 6, l = tid & 63;
  int wr = w >> 1, wc = w & 1;
  int src_off = SRC_OFF(l);
  int rd_off  = RD_OFF(l);

  int rt = tid >> 4;
  int c4 = tid & 15;
  int h_thr = c4 >> 3;
  int cw = c4 & 7;
  const float* athr = ctx + (size_t)(row0 + rt) * D_ + 4 * c4;
  int aw_base = rt * 64 + ((cw >> 1) ^ ((rt >> 1) & 3)) * 16 + (cw & 1) * 8;
  char* aw_ptr0 = (char*)&As[0 + h_thr][0] + aw_base;   // buf 0
  char* aw_ptr1 = (char*)&As[2 + h_thr][0] + aw_base;   // buf 1

  f32x4 acc[4][4];
#pragma unroll
  for (int m = 0; m < 4; ++m)
#pragma unroll
    for (int n = 0; n < 4; ++n) acc[m][n] = (f32x4){0.f, 0.f, 0.f, 0.f};

  float4 ap0, ap1, ap2, ap3, ap4, ap5, ap6, ap7;
  ap0 = *(const float4*)(athr + 0 * 12288);
  ap1 = *(const float4*)(athr + 1 * 12288);
  ap2 = *(const float4*)(athr + 2 * 12288);
  ap3 = *(const float4*)(athr + 3 * 12288);
  ap4 = *(const float4*)(athr + 4 * 12288);
  ap5 = *(const float4*)(athr + 5 * 12288);
  ap6 = *(const float4*)(athr + 6 * 12288);
  ap7 = *(const float4*)(athr + 7 * 12288);

  // ---- prologue: stage kt=0 into buf 0; prefetch A regs kt=64 ----
  {
    uint2 d;
    d.x = cvtpk(ap0.x, ap0.y); d.y = cvtpk(ap0.z, ap0.w);
    *(uint2*)(aw_ptr0 + 0 * 1024) = d;
    d.x = cvtpk(ap1.x, ap1.y); d.y = cvtpk(ap1.z, ap1.w);
    *(uint2*)(aw_ptr0 + 1 * 1024) = d;
    d.x = cvtpk(ap2.x, ap2.y); d.y = cvtpk(ap2.z, ap2.w);
    *(uint2*)(aw_ptr0 + 2 * 1024) = d;
    d.x = cvtpk(ap3.x, ap3.y); d.y = cvtpk(ap3.z, ap3.w);
    *(uint2*)(aw_ptr0 + 3 * 1024) = d;
    d.x = cvtpk(ap4.x, ap4.y); d.y = cvtpk(ap4.z, ap4.w);
    *(uint2*)(aw_ptr0 + 4 * 1024) = d;
    d.x = cvtpk(ap5.x, ap5.y); d.y = cvtpk(ap5.z, ap5.w);
    *(uint2*)(aw_ptr0 + 5 * 1024) = d;
    d.x = cvtpk(ap6.x, ap6.y); d.y = cvtpk(ap6.z, ap6.w);
    *(uint2*)(aw_ptr0 + 6 * 1024) = d;
    d.x = cvtpk(ap7.x, ap7.y); d.y = cvtpk(ap7.z, ap7.w);
    *(uint2*)(aw_ptr0 + 7 * 1024) = d;
#pragma unroll
    for (int hh = 0; hh < 2; ++hh)
#pragma unroll
      for (int g = 0; g < 2; ++g) {
        int grp = w * 2 + g;
        int grow = grp * 16 + (l >> 2);
        const ushort* bsrc = Mt + (size_t)(col0 + grow) * D_ + hh * 32 + src_off;
        gload16(bsrc, (char*)Bs[hh] + grp * 1024);
      }
    const float* an = athr + 64;
    ap0 = *(const float4*)(an + 0 * 12288);
    ap1 = *(const float4*)(an + 1 * 12288);
    ap2 = *(const float4*)(an + 2 * 12288);
    ap3 = *(const float4*)(an + 3 * 12288);
    ap4 = *(const float4*)(an + 4 * 12288);
    ap5 = *(const float4*)(an + 5 * 12288);
    ap6 = *(const float4*)(an + 6 * 12288);
    ap7 = *(const float4*)(an + 7 * 12288);
  }
  __syncthreads();  // buf0 ready

  for (int i = 0; i < 12; ++i) {
    int cur = i & 1, nxt = cur ^ 1;
    if (i < 11) {
      int ktn = (i + 1) * 64;   // ap regs hold this kt's A data
      char* awp = nxt ? aw_ptr1 : aw_ptr0;
      uint2 d;
      d.x = cvtpk(ap0.x, ap0.y); d.y = cvtpk(ap0.z, ap0.w);
      *(uint2*)(awp + 0 * 1024) = d;
      d.x = cvtpk(ap1.x, ap1.y); d.y = cvtpk(ap1.z, ap1.w);
      *(uint2*)(awp + 1 * 1024) = d;
      d.x = cvtpk(ap2.x, ap2.y); d.y = cvtpk(ap2.z, ap2.w);
      *(uint2*)(awp + 2 * 1024) = d;
      d.x = cvtpk(ap3.x, ap3.y); d.y = cvtpk(ap3.z, ap3.w);
      *(uint2*)(awp + 3 * 1024) = d;
      d.x = cvtpk(ap4.x, ap4.y); d.y = cvtpk(ap4.z, ap4.w);
      *(uint2*)(awp + 4 * 1024) = d;
      d.x = cvtpk(ap5.x, ap5.y); d.y = cvtpk(ap5.z, ap5.w);
      *(uint2*)(awp + 5 * 1024) = d;
      d.x = cvtpk(ap6.x, ap6.y); d.y = cvtpk(ap6.z, ap6.w);
      *(uint2*)(awp + 6 * 1024) = d;
      d.x = cvtpk(ap7.x, ap7.y); d.y = cvtpk(ap7.z, ap7.w);
      *(uint2*)(awp + 7 * 1024) = d;
#pragma unroll
      for (int hh = 0; hh < 2; ++hh)
#pragma unroll
        for (int g = 0; g < 2; ++g) {
          int grp = w * 2 + g;
          int grow = grp * 16 + (l >> 2);
          const ushort* bsrc = Mt + (size_t)(col0 + grow) * D_ + ktn + hh * 32 + src_off;
          gload16(bsrc, (char*)Bs[nxt * 2 + hh] + grp * 1024);
        }
      if (i < 10) {
        const float* an = athr + ktn + 64;
        ap0 = *(const float4*)(an + 0 * 12288);
        ap1 = *(const float4*)(an + 1 * 12288);
        ap2 = *(const float4*)(an + 2 * 12288);
        ap3 = *(const float4*)(an + 3 * 12288);
        ap4 = *(const float4*)(an + 4 * 12288);
        ap5 = *(const float4*)(an + 5 * 12288);
        ap6 = *(const float4*)(an + 6 * 12288);
        ap7 = *(const float4*)(an + 7 * 12288);
      }
    }
    // compute on buf cur
#pragma unroll
    for (int hh = 0; hh < 2; ++hh) {
      bf16x8 af[4], bfr[4];
#pragma unroll
      for (int m = 0; m < 4; ++m)
        af[m] = *(const bf16x8*)&As[cur * 2 + hh][(wr * 64 + m * 16 + (l & 15)) * 32 + rd_off];
#pragma unroll
      for (int n = 0; n < 4; ++n)
        bfr[n] = *(const bf16x8*)&Bs[cur * 2 + hh][(wc * 64 + n * 16 + (l & 15)) * 32 + rd_off];
#pragma unroll
      for (int m = 0; m < 4; ++m)
#pragma unroll
        for (int n = 0; n < 4; ++n)
          acc[m][n] = __builtin_amdgcn_mfma_f32_16x16x32_bf16(af[m], bfr[n], acc[m][n], 0, 0, 0);
    }
    __syncthreads();  // nxt staged + cur reads done
  }

  int rbase = row0 + wr * 64;
  int cbase = col0 + wc * 64;
#pragma unroll
  for (int m = 0; m < 4; ++m)
#pragma unroll
    for (int n = 0; n < 4; ++n)
#pragma unroll
      for (int i = 0; i < 4; ++i) {
        int rr = rbase + m * 16 + (l >> 4) * 4 + i;
        int cc = cbase + n * 16 + (l & 15);
        qm[(size_t)rr * D_ + cc] = f2bf(acc[m][n][i]);
      }
}

// ---------------- k_attn: full fusion, DOUBLE-BUFFERED (R13, unchanged) ----
__global__ __launch_bounds__(1024) void k_attn(const ushort* __restrict__ qm,
                                               const float* __restrict__ cand,
                                               const int* __restrict__ cand_mask,
                                               const int* __restrict__ ctx_mask,
                                               const float* __restrict__ WV,
                                               float* __restrict__ xbuf) {
  __shared__ __align__(16) ushort As[4][PANEL256];   // 65.8 KB
  __shared__ __align__(16) ushort Bs[4][PANEL256];   // 65.8 KB
  __shared__ float wv_lds[D_];
  __shared__ float w_lds[256];
  __shared__ float xpart[4][256];
  int b = blockIdx.x;
  int tid = threadIdx.x;
  int w = tid >> 6, l = tid & 63;
  int wr = w >> 2, wc = w & 3;             // 4x4 wave grid
  int src_off = SRC_OFF(l);
  int rd_off  = RD_OFF(l);

  if (tid < D_) wv_lds[tid] = WV[tid];

  int rt = tid >> 4;
  int c4 = tid & 15;
  int h_thr = c4 >> 3;
  int cw = c4 & 7;
  int row_k0 = rt, row_k1 = rt + 64, row_k2 = rt + 128, row_k3 = rt + 192;
  int ok3 = row_k3 < S_;                   // only k=3 can be out of range
  const float* bptr0 = cand + ((size_t)b * S_ + row_k0) * D_ + 4 * c4;
  const float* bptr1 = cand + ((size_t)b * S_ + row_k1) * D_ + 4 * c4;
  const float* bptr2 = cand + ((size_t)b * S_ + row_k2) * D_ + 4 * c4;
  const float* bptr3 = cand + ((size_t)b * S_ + (ok3 ? row_k3 : S_ - 1)) * D_ + 4 * c4;
  int bw_base = rt * 64 + ((cw >> 1) ^ ((rt >> 1) & 3)) * 16 + (cw & 1) * 8;

  f32x4 acc[4][4];
#pragma unroll
  for (int m = 0; m < 4; ++m)
#pragma unroll
    for (int n = 0; n < 4; ++n) acc[m][n] = (f32x4){0.f, 0.f, 0.f, 0.f};
  float wa0 = 0.f, wa1 = 0.f, wa2 = 0.f, wa3 = 0.f;

  size_t arow = (size_t)b * 256;
  __syncthreads();  // wv_lds ready

  float4 bp0 = *(const float4*)(bptr0);
  float4 bp1 = *(const float4*)(bptr1);
  float4 bp2 = *(const float4*)(bptr2);
  float4 bp3 = *(const float4*)(bptr3);
  if (!ok3) bp3 = (float4){0.f, 0.f, 0.f, 0.f};

  // ---- prologue: stage kt=0 into buf 0, wacc(kt0), prefetch kt=64 ----
  {
    char* bw_ptr = (char*)&Bs[h_thr][0] + bw_base;
    uint2 d;
    d.x = cvtpk(bp0.x, bp0.y); d.y = cvtpk(bp0.z, bp0.w);
    *(uint2*)(bw_ptr + 0 * 4096) = d;
    d.x = cvtpk(bp1.x, bp1.y); d.y = cvtpk(bp1.z, bp1.w);
    *(uint2*)(bw_ptr + 1 * 4096) = d;
    d.x = cvtpk(bp2.x, bp2.y); d.y = cvtpk(bp2.z, bp2.w);
    *(uint2*)(bw_ptr + 2 * 4096) = d;
    d.x = cvtpk(bp3.x, bp3.y); d.y = cvtpk(bp3.z, bp3.w);
    *(uint2*)(bw_ptr + 3 * 4096) = d;
#pragma unroll
    for (int h = 0; h < 2; ++h) {
      const ushort* gsrc = qm + (arow + w * 16 + (l >> 2)) * D_ + h * 32 + src_off;
      gload16(gsrc, (char*)As[h] + w * 1024);
    }
    float4 wv = *(const float4*)&wv_lds[4 * c4];
    wa0 += bp0.x * wv.x + bp0.y * wv.y + bp0.z * wv.z + bp0.w * wv.w;
    wa1 += bp1.x * wv.x + bp1.y * wv.y + bp1.z * wv.z + bp1.w * wv.w;
    wa2 += bp2.x * wv.x + bp2.y * wv.y + bp2.z * wv.z + bp2.w * wv.w;
    wa3 += bp3.x * wv.x + bp3.y * wv.y + bp3.z * wv.z + bp3.w * wv.w;
    bp0 = *(const float4*)(bptr0 + 64);
    bp1 = *(const float4*)(bptr1 + 64);
    bp2 = *(const float4*)(bptr2 + 64);
    bp3 = *(const float4*)(bptr3 + 64);
    if (!ok3) bp3 = (float4){0.f, 0.f, 0.f, 0.f};
  }
  __syncthreads();  // buf0 ready

  for (int i = 0; i < 12; ++i) {
    int cur = i & 1, nxt = cur ^ 1;
    if (i < 11) {
      int ktn = (i + 1) * 64;  // bp holds this kt's data
      // stage kt+64 into buf nxt
      char* bw_ptr = (char*)&Bs[nxt * 2 + h_thr][0] + bw_base;
      uint2 d;
      d.x = cvtpk(bp0.x, bp0.y); d.y = cvtpk(bp0.z, bp0.w);
      *(uint2*)(bw_ptr + 0 * 4096) = d;
      d.x = cvtpk(bp1.x, bp1.y); d.y = cvtpk(bp1.z, bp1.w);
      *(uint2*)(bw_ptr + 1 * 4096) = d;
      d.x = cvtpk(bp2.x, bp2.y); d.y = cvtpk(bp2.z, bp2.w);
      *(uint2*)(bw_ptr + 2 * 4096) = d;
      d.x = cvtpk(bp3.x, bp3.y); d.y = cvtpk(bp3.z, bp3.w);
      *(uint2*)(bw_ptr + 3 * 4096) = d;
#pragma unroll
      for (int h = 0; h < 2; ++h) {
        const ushort* gsrc = qm + (arow + w * 16 + (l >> 2)) * D_ + ktn + h * 32 + src_off;
        gload16(gsrc, (char*)As[nxt * 2 + h] + w * 1024);
      }
      float4 wv = *(const float4*)&wv_lds[ktn + 4 * c4];
      wa0 += bp0.x * wv.x + bp0.y * wv.y + bp0.z * wv.z + bp0.w * wv.w;
      wa1 += bp1.x * wv.x + bp1.y * wv.y + bp1.z * wv.z + bp1.w * wv.w;
      wa2 += bp2.x * wv.x + bp2.y * wv.y + bp2.z * wv.z + bp2.w * wv.w;
      wa3 += bp3.x * wv.x + bp3.y * wv.y + bp3.z * wv.z + bp3.w * wv.w;
      if (i < 10) {
        int ktn2 = ktn + 64;
        bp0 = *(const float4*)(bptr0 + ktn2);
        bp1 = *(const float4*)(bptr1 + ktn2);
        bp2 = *(const float4*)(bptr2 + ktn2);
        bp3 = *(const float4*)(bptr3 + ktn2);
        if (!ok3) bp3 = (float4){0.f, 0.f, 0.f, 0.f};
      }
    }
    // compute on buf cur
#pragma unroll
    for (int h = 0; h < 2; ++h) {
      bf16x8 af[4], bfr[4];
#pragma unroll
      for (int m = 0; m < 4; ++m)
        af[m] = *(const bf16x8*)&As[cur * 2 + h][(wr * 64 + m * 16 + (l & 15)) * 32 + rd_off];
#pragma unroll
      for (int n = 0; n < 4; ++n)
        bfr[n] = *(const bf16x8*)&Bs[cur * 2 + h][(wc * 64 + n * 16 + (l & 15)) * 32 + rd_off];
#pragma unroll
      for (int m = 0; m < 4; ++m)
#pragma unroll
        for (int n = 0; n < 4; ++n)
          acc[m][n] = __builtin_amdgcn_mfma_f32_16x16x32_bf16(af[m], bfr[n], acc[m][n], 0, 0, 0);
    }
    __syncthreads();  // next buf staged + this buf's reads done
  }

  // finish w: 16-lane (c4) shfl reduce, then mask & publish
  wa0 += __shfl_xor(wa0, 1, 64); wa0 += __shfl_xor(wa0, 2, 64);
  wa0 += __shfl_xor(wa0, 4, 64); wa0 += __shfl_xor(wa0, 8, 64);
  wa1 += __shfl_xor(wa1, 1, 64); wa1 += __shfl_xor(wa1, 2, 64);
  wa1 += __shfl_xor(wa1, 4, 64); wa1 += __shfl_xor(wa1, 8, 64);
  wa2 += __shfl_xor(wa2, 1, 64); wa2 += __shfl_xor(wa2, 2, 64);
  wa2 += __shfl_xor(wa2, 4, 64); wa2 += __shfl_xor(wa2, 8, 64);
  wa3 += __shfl_xor(wa3, 1, 64); wa3 += __shfl_xor(wa3, 2, 64);
  wa3 += __shfl_xor(wa3, 4, 64); wa3 += __shfl_xor(wa3, 8, 64);
  if (c4 == 0) {
    const int* cm = cand_mask + (size_t)b * S_;
    w_lds[row_k0] = (cm[row_k0] != 0) ? wa0 : 0.f;
    w_lds[row_k1] = (cm[row_k1] != 0) ? wa1 : 0.f;
    w_lds[row_k2] = (cm[row_k2] != 0) ? wa2 : 0.f;
    w_lds[row_k3] = (ok3 && cm[ok3 ? row_k3 : 0] != 0) ? wa3 : 0.f;
  }
  __syncthreads();

  float rs[4][4];
#pragma unroll
  for (int m = 0; m < 4; ++m)
#pragma unroll
    for (int i = 0; i < 4; ++i) rs[m][i] = 0.f;

#pragma unroll
  for (int n = 0; n < 4; ++n) {
    float wcol = w_lds[wc * 64 + n * 16 + (l & 15)];
#pragma unroll
    for (int m = 0; m < 4; ++m)
#pragma unroll
      for (int i = 0; i < 4; ++i) {
        float p = 1.f / (1.f + __expf(-acc[m][n][i]));
        rs[m][i] += p * wcol;
      }
  }
#pragma unroll
  for (int m = 0; m < 4; ++m)
#pragma unroll
    for (int i = 0; i < 4; ++i) {
      float v = rs[m][i];
      v += __shfl_xor(v, 1, 64);
      v += __shfl_xor(v, 2, 64);
      v += __shfl_xor(v, 4, 64);
      v += __shfl_xor(v, 8, 64);
      rs[m][i] = v;
    }
  if ((l & 15) == 0) {
#pragma unroll
    for (int m = 0; m < 4; ++m)
#pragma unroll
      for (int i = 0; i < 4; ++i)
        xpart[wc][wr * 64 + m * 16 + (l >> 4) * 4 + i] = rs[m][i];
  }
  __syncthreads();
  if (tid < 256) {
    float xs = xpart[0][tid] + xpart[1][tid] + xpart[2][tid] + xpart[3][tid];
    int gm = ctx_mask[(size_t)b * 256 + tid];
    xbuf[(size_t)b * 256 + tid] = gm ? xs : 0.f;
  }
}

// ---------------- k_mlp: y[b] = (x[b]^T W1 + b1) W2 + b2 -------------------
__global__ __launch_bounds__(128) void k_mlp(const float* __restrict__ xbuf,
                                             const float* __restrict__ W1,
                                             const float* __restrict__ b1,
                                             const float* __restrict__ W2,
                                             const float* __restrict__ b2,
                                             float* __restrict__ out) {
  int b = blockIdx.x, t = threadIdx.x;
  __shared__ float xl[256];
  __shared__ float hl[128];
  xl[t]       = xbuf[(size_t)b * 256 + t];
  xl[t + 128] = xbuf[(size_t)b * 256 + 128 + t];
  __syncthreads();
  float acc = b1[t];
#pragma unroll 8
  for (int ll = 0; ll < 256; ++ll) acc += xl[ll] * W1[ll * H_ + t];
  hl[t] = acc;
  __syncthreads();
  if (t < 5) {
    float y = b2[t];
#pragma unroll 8
    for (int h = 0; h < H_; ++h) y += hl[h] * W2[h * 5 + t];
    out[(size_t)b * 5 + t] = y;
  }
}

extern "C" void kernel_launch(void* const* d_in, const int* in_sizes, int n_in,
                              void* d_out, int out_size, void* d_ws, size_t ws_size,
                              hipStream_t stream) {
  const float* ctx       = (const float*)d_in[0];
  const float* cand      = (const float*)d_in[1];
  const int*   ctx_mask  = (const int*)d_in[2];
  const int*   cand_mask = (const int*)d_in[3];
  const float* WK        = (const float*)d_in[4];
  const float* WQ        = (const float*)d_in[5];
  const float* WV        = (const float*)d_in[6];
  const float* W1        = (const float*)d_in[7];
  const float* b1        = (const float*)d_in[8];
  const float* W2        = (const float*)d_in[9];
  const float* b2        = (const float*)d_in[10];
  float* out = (float*)d_out;

  char* ws = (char*)d_ws;
  size_t off = 0;
  auto alloc = [&](size_t bytes) {
    void* p = ws + off;
    off += (bytes + 255) & ~(size_t)255;
    return p;
  };
  ushort* Mt   = (ushort*)alloc((size_t)D_ * D_ * 2);        // 1.18 MB
  ushort* wqb  = (ushort*)alloc((size_t)D_ * D_ * 2);        // 1.18 MB
  float*  xbuf = (float*) alloc((size_t)B_ * L_ * 4);        // 256 KB
  ushort* qm   = (ushort*)alloc((size_t)B_ * L_ * D_ * 2);   // 100.7 MB
  (void)ws_size; (void)in_sizes; (void)n_in; (void)out_size;

  k_wqb <<<D_ * D_ / 4 / 256,  256, 0, stream>>>(WQ, wqb);
  k_mtm <<<36,                 256, 0, stream>>>(WK, wqb, Mt);
  k_qm  <<<B_ * L_ / 128 * 6,  256, 0, stream>>>(ctx, Mt, qm);
  k_attn<<<B_,                1024, 0, stream>>>(qm, cand, cand_mask, ctx_mask, WV, xbuf);
  k_mlp <<<B_,                 128, 0, stream>>>(xbuf, W1, b1, W2, b2, out);
}

// Round 15
// 250.332 us; speedup vs baseline: 1.1700x; 1.1700x over previous
//
#include <hip/hip_runtime.h>
#include <hip/hip_bf16.h>
#include <stdint.h>

#define B_  256
#define L_  256
#define S_  253
#define D_  768
#define H_  128

typedef __bf16 bf16x8 __attribute__((ext_vector_type(8)));
typedef float  f32x4  __attribute__((ext_vector_type(4)));

__device__ __forceinline__ ushort f2bf(float f) {
  union { float f; uint32_t u; } v; v.f = f;
  uint32_t r = v.u + 0x7FFFu + ((v.u >> 16) & 1u);  // RNE
  return (ushort)(r >> 16);
}

__device__ __forceinline__ uint32_t cvtpk(float lo, float hi) {
  uint32_t r;
  asm("v_cvt_pk_bf16_f32 %0, %1, %2" : "=v"(r) : "v"(lo), "v"(hi));
  return r;
}

__device__ __forceinline__ void gload16(const void* g, void* l) {
  __builtin_amdgcn_global_load_lds((const __attribute__((address_space(1))) void*)g,
                                   (__attribute__((address_space(3))) void*)l,
                                   16, 0, 0);
}

// Bank swizzle (verified R5: read conflicts -> 0). LDS rows of 32 ushort =
// 4 slots of 16 B; stored slot s at row r holds global slot s ^ ((r>>1)&3).
// k_qm: single-buffer 2-barrier form is the proven best (R11/R13 ~159us);
// dbuf (R14, -1 resident block) and retiles (R12) both regressed.
#define SRC_OFF(l) ((((l) & 3) ^ (((l) >> 3) & 3)) * 8)
#define RD_OFF(l)  (((((l) >> 4) ^ (((l) >> 1) & 3))) * 8)
#define PANEL128 (128 * 32)
#define PANEL256 (256 * 32 + 32)

// ---------------- k_wqb: WQ f32 -> bf16 row-copy ----------------------------
__global__ __launch_bounds__(256) void k_wqb(const float* __restrict__ WQ,
                                             ushort* __restrict__ wqb) {
  int i = blockIdx.x * 256 + threadIdx.x;   // 147456 float4s exactly
  float4 c = ((const float4*)WQ)[i];
  ushort4 o;
  o.x = f2bf(c.x); o.y = f2bf(c.y); o.z = f2bf(c.z); o.w = f2bf(c.w);
  ((ushort4*)wqb)[i] = o;
}

// ---------------- k_mtm: Mt[i][j] = scale * sum_t WK[i,t]*WQ[j,t] (MFMA) ----
__global__ __launch_bounds__(256) void k_mtm(const float* __restrict__ WK,
                                             const ushort* __restrict__ wqb,
                                             ushort* __restrict__ Mt) {
  const float scale = 0.03608439182435161f;  // 1/sqrt(768)
  __shared__ __align__(16) ushort As[2][PANEL128];
  __shared__ __align__(16) ushort Bs[2][PANEL128];
  int bm = blockIdx.x / 6, bn = blockIdx.x % 6;
  int row0 = bm * 128, col0 = bn * 128;
  int tid = threadIdx.x;
  int w = tid >> 6, l = tid & 63;
  int wr = w >> 1, wc = w & 1;
  int src_off = SRC_OFF(l);
  int rd_off  = RD_OFF(l);

  int rt = tid >> 4;
  int c4 = tid & 15;
  int h_thr = c4 >> 3;
  int cw = c4 & 7;
  const float* athr = WK + (size_t)(row0 + rt) * D_ + 4 * c4;
  int aw_base = rt * 64 + ((cw >> 1) ^ ((rt >> 1) & 3)) * 16 + (cw & 1) * 8;
  char* aw_ptr = (char*)&As[h_thr][0] + aw_base;

  f32x4 acc[4][4];
#pragma unroll
  for (int m = 0; m < 4; ++m)
#pragma unroll
    for (int n = 0; n < 4; ++n) acc[m][n] = (f32x4){0.f, 0.f, 0.f, 0.f};

  float4 ap0, ap1, ap2, ap3, ap4, ap5, ap6, ap7;
  ap0 = *(const float4*)(athr + 0 * 12288);
  ap1 = *(const float4*)(athr + 1 * 12288);
  ap2 = *(const float4*)(athr + 2 * 12288);
  ap3 = *(const float4*)(athr + 3 * 12288);
  ap4 = *(const float4*)(athr + 4 * 12288);
  ap5 = *(const float4*)(athr + 5 * 12288);
  ap6 = *(const float4*)(athr + 6 * 12288);
  ap7 = *(const float4*)(athr + 7 * 12288);

  for (int i = 0; i < 12; ++i) {
    int kt = i * 64;
    if (i) __syncthreads();
    {
      uint2 d;
      d.x = cvtpk(ap0.x, ap0.y); d.y = cvtpk(ap0.z, ap0.w);
      *(uint2*)(aw_ptr + 0 * 1024) = d;
      d.x = cvtpk(ap1.x, ap1.y); d.y = cvtpk(ap1.z, ap1.w);
      *(uint2*)(aw_ptr + 1 * 1024) = d;
      d.x = cvtpk(ap2.x, ap2.y); d.y = cvtpk(ap2.z, ap2.w);
      *(uint2*)(aw_ptr + 2 * 1024) = d;
      d.x = cvtpk(ap3.x, ap3.y); d.y = cvtpk(ap3.z, ap3.w);
      *(uint2*)(aw_ptr + 3 * 1024) = d;
      d.x = cvtpk(ap4.x, ap4.y); d.y = cvtpk(ap4.z, ap4.w);
      *(uint2*)(aw_ptr + 4 * 1024) = d;
      d.x = cvtpk(ap5.x, ap5.y); d.y = cvtpk(ap5.z, ap5.w);
      *(uint2*)(aw_ptr + 5 * 1024) = d;
      d.x = cvtpk(ap6.x, ap6.y); d.y = cvtpk(ap6.z, ap6.w);
      *(uint2*)(aw_ptr + 6 * 1024) = d;
      d.x = cvtpk(ap7.x, ap7.y); d.y = cvtpk(ap7.z, ap7.w);
      *(uint2*)(aw_ptr + 7 * 1024) = d;
    }
#pragma unroll
    for (int hh = 0; hh < 2; ++hh)
#pragma unroll
      for (int g = 0; g < 2; ++g) {
        int grp = w * 2 + g;
        int grow = grp * 16 + (l >> 2);
        const ushort* bsrc = wqb + (size_t)(col0 + grow) * D_ + kt + hh * 32 + src_off;
        gload16(bsrc, (char*)Bs[hh] + grp * 1024);
      }
    {
      int ktn = (i < 11) ? kt + 64 : kt;
      const float* an = athr + ktn;
      ap0 = *(const float4*)(an + 0 * 12288);
      ap1 = *(const float4*)(an + 1 * 12288);
      ap2 = *(const float4*)(an + 2 * 12288);
      ap3 = *(const float4*)(an + 3 * 12288);
      ap4 = *(const float4*)(an + 4 * 12288);
      ap5 = *(const float4*)(an + 5 * 12288);
      ap6 = *(const float4*)(an + 6 * 12288);
      ap7 = *(const float4*)(an + 7 * 12288);
    }
    __syncthreads();

#pragma unroll
    for (int hh = 0; hh < 2; ++hh) {
      bf16x8 af[4], bfr[4];
#pragma unroll
      for (int m = 0; m < 4; ++m)
        af[m] = *(const bf16x8*)&As[hh][(wr * 64 + m * 16 + (l & 15)) * 32 + rd_off];
#pragma unroll
      for (int n = 0; n < 4; ++n)
        bfr[n] = *(const bf16x8*)&Bs[hh][(wc * 64 + n * 16 + (l & 15)) * 32 + rd_off];
#pragma unroll
      for (int m = 0; m < 4; ++m)
#pragma unroll
        for (int n = 0; n < 4; ++n)
          acc[m][n] = __builtin_amdgcn_mfma_f32_16x16x32_bf16(af[m], bfr[n], acc[m][n], 0, 0, 0);
    }
  }

  int rbase = row0 + wr * 64;
  int cbase = col0 + wc * 64;
#pragma unroll
  for (int m = 0; m < 4; ++m)
#pragma unroll
    for (int n = 0; n < 4; ++n)
#pragma unroll
      for (int i = 0; i < 4; ++i) {
        int rr = rbase + m * 16 + (l >> 4) * 4 + i;
        int cc = cbase + n * 16 + (l & 15);
        Mt[(size_t)rr * D_ + cc] = f2bf(acc[m][n][i] * scale);
      }
}

// ---------------- k_qm: qm[r][c] = sum_k ctx[r][k] * Mt[c][k]  (bf16) -------
// R11/R13-exact: single-buffer, 2-barrier, reg-prefetch A one iter ahead,
// gload_lds B, 128x128 tile, LDS 32KB (best measured; dbuf/retile regressed).
__global__ __launch_bounds__(256) void k_qm(const float* __restrict__ ctx,
                                            const ushort* __restrict__ Mt,
                                            ushort* __restrict__ qm) {
  __shared__ __align__(16) ushort As[2][PANEL128];
  __shared__ __align__(16) ushort Bs[2][PANEL128];
  int bid0 = blockIdx.x;              // 0..3071
  int xcd = bid0 & 7;
  int idx = bid0 >> 3;                // 0..383
  int bm = xcd * 64 + idx / 6;        // 0..511 (bijective)
  int bn = idx % 6;
  int row0 = bm * 128, col0 = bn * 128;
  int tid = threadIdx.x;
  int w = tid >> 6, l = tid & 63;
  int wr = w >> 1, wc = w & 1;
  int src_off = SRC_OFF(l);
  int rd_off  = RD_OFF(l);

  int rt = tid >> 4;
  int c4 = tid & 15;
  int h_thr = c4 >> 3;
  int cw = c4 & 7;
  const float* athr = ctx + (size_t)(row0 + rt) * D_ + 4 * c4;
  int aw_base = rt * 64 + ((cw >> 1) ^ ((rt >> 1) & 3)) * 16 + (cw & 1) * 8;
  char* aw_ptr = (char*)&As[h_thr][0] + aw_base;

  f32x4 acc[4][4];
#pragma unroll
  for (int m = 0; m < 4; ++m)
#pragma unroll
    for (int n = 0; n < 4; ++n) acc[m][n] = (f32x4){0.f, 0.f, 0.f, 0.f};

  float4 ap0, ap1, ap2, ap3, ap4, ap5, ap6, ap7;
  ap0 = *(const float4*)(athr + 0 * 12288);
  ap1 = *(const float4*)(athr + 1 * 12288);
  ap2 = *(const float4*)(athr + 2 * 12288);
  ap3 = *(const float4*)(athr + 3 * 12288);
  ap4 = *(const float4*)(athr + 4 * 12288);
  ap5 = *(const float4*)(athr + 5 * 12288);
  ap6 = *(const float4*)(athr + 6 * 12288);
  ap7 = *(const float4*)(athr + 7 * 12288);

  for (int i = 0; i < 12; ++i) {
    int kt = i * 64;
    if (i) __syncthreads();
    {
      uint2 d;
      d.x = cvtpk(ap0.x, ap0.y); d.y = cvtpk(ap0.z, ap0.w);
      *(uint2*)(aw_ptr + 0 * 1024) = d;
      d.x = cvtpk(ap1.x, ap1.y); d.y = cvtpk(ap1.z, ap1.w);
      *(uint2*)(aw_ptr + 1 * 1024) = d;
      d.x = cvtpk(ap2.x, ap2.y); d.y = cvtpk(ap2.z, ap2.w);
      *(uint2*)(aw_ptr + 2 * 1024) = d;
      d.x = cvtpk(ap3.x, ap3.y); d.y = cvtpk(ap3.z, ap3.w);
      *(uint2*)(aw_ptr + 3 * 1024) = d;
      d.x = cvtpk(ap4.x, ap4.y); d.y = cvtpk(ap4.z, ap4.w);
      *(uint2*)(aw_ptr + 4 * 1024) = d;
      d.x = cvtpk(ap5.x, ap5.y); d.y = cvtpk(ap5.z, ap5.w);
      *(uint2*)(aw_ptr + 5 * 1024) = d;
      d.x = cvtpk(ap6.x, ap6.y); d.y = cvtpk(ap6.z, ap6.w);
      *(uint2*)(aw_ptr + 6 * 1024) = d;
      d.x = cvtpk(ap7.x, ap7.y); d.y = cvtpk(ap7.z, ap7.w);
      *(uint2*)(aw_ptr + 7 * 1024) = d;
    }
#pragma unroll
    for (int hh = 0; hh < 2; ++hh)
#pragma unroll
      for (int g = 0; g < 2; ++g) {
        int grp = w * 2 + g;
        int grow = grp * 16 + (l >> 2);
        const ushort* bsrc = Mt + (size_t)(col0 + grow) * D_ + kt + hh * 32 + src_off;
        gload16(bsrc, (char*)Bs[hh] + grp * 1024);
      }
    {
      int ktn = (i < 11) ? kt + 64 : kt;
      const float* an = athr + ktn;
      ap0 = *(const float4*)(an + 0 * 12288);
      ap1 = *(const float4*)(an + 1 * 12288);
      ap2 = *(const float4*)(an + 2 * 12288);
      ap3 = *(const float4*)(an + 3 * 12288);
      ap4 = *(const float4*)(an + 4 * 12288);
      ap5 = *(const float4*)(an + 5 * 12288);
      ap6 = *(const float4*)(an + 6 * 12288);
      ap7 = *(const float4*)(an + 7 * 12288);
    }
    __syncthreads();

#pragma unroll
    for (int hh = 0; hh < 2; ++hh) {
      bf16x8 af[4], bfr[4];
#pragma unroll
      for (int m = 0; m < 4; ++m)
        af[m] = *(const bf16x8*)&As[hh][(wr * 64 + m * 16 + (l & 15)) * 32 + rd_off];
#pragma unroll
      for (int n = 0; n < 4; ++n)
        bfr[n] = *(const bf16x8*)&Bs[hh][(wc * 64 + n * 16 + (l & 15)) * 32 + rd_off];
#pragma unroll
      for (int m = 0; m < 4; ++m)
#pragma unroll
        for (int n = 0; n < 4; ++n)
          acc[m][n] = __builtin_amdgcn_mfma_f32_16x16x32_bf16(af[m], bfr[n], acc[m][n], 0, 0, 0);
    }
  }

  int rbase = row0 + wr * 64;
  int cbase = col0 + wc * 64;
#pragma unroll
  for (int m = 0; m < 4; ++m)
#pragma unroll
    for (int n = 0; n < 4; ++n)
#pragma unroll
      for (int i = 0; i < 4; ++i) {
        int rr = rbase + m * 16 + (l >> 4) * 4 + i;
        int cc = cbase + n * 16 + (l & 15);
        qm[(size_t)rr * D_ + cc] = f2bf(acc[m][n][i]);
      }
}

// ---------------- k_attn: full fusion, DOUBLE-BUFFERED (R13, unchanged) ----
__global__ __launch_bounds__(1024) void k_attn(const ushort* __restrict__ qm,
                                               const float* __restrict__ cand,
                                               const int* __restrict__ cand_mask,
                                               const int* __restrict__ ctx_mask,
                                               const float* __restrict__ WV,
                                               float* __restrict__ xbuf) {
  __shared__ __align__(16) ushort As[4][PANEL256];   // 65.8 KB
  __shared__ __align__(16) ushort Bs[4][PANEL256];   // 65.8 KB
  __shared__ float wv_lds[D_];
  __shared__ float w_lds[256];
  __shared__ float xpart[4][256];
  int b = blockIdx.x;
  int tid = threadIdx.x;
  int w = tid >> 6, l = tid & 63;
  int wr = w >> 2, wc = w & 3;             // 4x4 wave grid
  int src_off = SRC_OFF(l);
  int rd_off  = RD_OFF(l);

  if (tid < D_) wv_lds[tid] = WV[tid];

  int rt = tid >> 4;
  int c4 = tid & 15;
  int h_thr = c4 >> 3;
  int cw = c4 & 7;
  int row_k0 = rt, row_k1 = rt + 64, row_k2 = rt + 128, row_k3 = rt + 192;
  int ok3 = row_k3 < S_;                   // only k=3 can be out of range
  const float* bptr0 = cand + ((size_t)b * S_ + row_k0) * D_ + 4 * c4;
  const float* bptr1 = cand + ((size_t)b * S_ + row_k1) * D_ + 4 * c4;
  const float* bptr2 = cand + ((size_t)b * S_ + row_k2) * D_ + 4 * c4;
  const float* bptr3 = cand + ((size_t)b * S_ + (ok3 ? row_k3 : S_ - 1)) * D_ + 4 * c4;
  int bw_base = rt * 64 + ((cw >> 1) ^ ((rt >> 1) & 3)) * 16 + (cw & 1) * 8;

  f32x4 acc[4][4];
#pragma unroll
  for (int m = 0; m < 4; ++m)
#pragma unroll
    for (int n = 0; n < 4; ++n) acc[m][n] = (f32x4){0.f, 0.f, 0.f, 0.f};
  float wa0 = 0.f, wa1 = 0.f, wa2 = 0.f, wa3 = 0.f;

  size_t arow = (size_t)b * 256;
  __syncthreads();  // wv_lds ready

  float4 bp0 = *(const float4*)(bptr0);
  float4 bp1 = *(const float4*)(bptr1);
  float4 bp2 = *(const float4*)(bptr2);
  float4 bp3 = *(const float4*)(bptr3);
  if (!ok3) bp3 = (float4){0.f, 0.f, 0.f, 0.f};

  // ---- prologue: stage kt=0 into buf 0, wacc(kt0), prefetch kt=64 ----
  {
    char* bw_ptr = (char*)&Bs[h_thr][0] + bw_base;
    uint2 d;
    d.x = cvtpk(bp0.x, bp0.y); d.y = cvtpk(bp0.z, bp0.w);
    *(uint2*)(bw_ptr + 0 * 4096) = d;
    d.x = cvtpk(bp1.x, bp1.y); d.y = cvtpk(bp1.z, bp1.w);
    *(uint2*)(bw_ptr + 1 * 4096) = d;
    d.x = cvtpk(bp2.x, bp2.y); d.y = cvtpk(bp2.z, bp2.w);
    *(uint2*)(bw_ptr + 2 * 4096) = d;
    d.x = cvtpk(bp3.x, bp3.y); d.y = cvtpk(bp3.z, bp3.w);
    *(uint2*)(bw_ptr + 3 * 4096) = d;
#pragma unroll
    for (int h = 0; h < 2; ++h) {
      const ushort* gsrc = qm + (arow + w * 16 + (l >> 2)) * D_ + h * 32 + src_off;
      gload16(gsrc, (char*)As[h] + w * 1024);
    }
    float4 wv = *(const float4*)&wv_lds[4 * c4];
    wa0 += bp0.x * wv.x + bp0.y * wv.y + bp0.z * wv.z + bp0.w * wv.w;
    wa1 += bp1.x * wv.x + bp1.y * wv.y + bp1.z * wv.z + bp1.w * wv.w;
    wa2 += bp2.x * wv.x + bp2.y * wv.y + bp2.z * wv.z + bp2.w * wv.w;
    wa3 += bp3.x * wv.x + bp3.y * wv.y + bp3.z * wv.z + bp3.w * wv.w;
    bp0 = *(const float4*)(bptr0 + 64);
    bp1 = *(const float4*)(bptr1 + 64);
    bp2 = *(const float4*)(bptr2 + 64);
    bp3 = *(const float4*)(bptr3 + 64);
    if (!ok3) bp3 = (float4){0.f, 0.f, 0.f, 0.f};
  }
  __syncthreads();  // buf0 ready

  for (int i = 0; i < 12; ++i) {
    int cur = i & 1, nxt = cur ^ 1;
    if (i < 11) {
      int ktn = (i + 1) * 64;  // bp holds this kt's data
      // stage kt+64 into buf nxt
      char* bw_ptr = (char*)&Bs[nxt * 2 + h_thr][0] + bw_base;
      uint2 d;
      d.x = cvtpk(bp0.x, bp0.y); d.y = cvtpk(bp0.z, bp0.w);
      *(uint2*)(bw_ptr + 0 * 4096) = d;
      d.x = cvtpk(bp1.x, bp1.y); d.y = cvtpk(bp1.z, bp1.w);
      *(uint2*)(bw_ptr + 1 * 4096) = d;
      d.x = cvtpk(bp2.x, bp2.y); d.y = cvtpk(bp2.z, bp2.w);
      *(uint2*)(bw_ptr + 2 * 4096) = d;
      d.x = cvtpk(bp3.x, bp3.y); d.y = cvtpk(bp3.z, bp3.w);
      *(uint2*)(bw_ptr + 3 * 4096) = d;
#pragma unroll
      for (int h = 0; h < 2; ++h) {
        const ushort* gsrc = qm + (arow + w * 16 + (l >> 2)) * D_ + ktn + h * 32 + src_off;
        gload16(gsrc, (char*)As[nxt * 2 + h] + w * 1024);
      }
      float4 wv = *(const float4*)&wv_lds[ktn + 4 * c4];
      wa0 += bp0.x * wv.x + bp0.y * wv.y + bp0.z * wv.z + bp0.w * wv.w;
      wa1 += bp1.x * wv.x + bp1.y * wv.y + bp1.z * wv.z + bp1.w * wv.w;
      wa2 += bp2.x * wv.x + bp2.y * wv.y + bp2.z * wv.z + bp2.w * wv.w;
      wa3 += bp3.x * wv.x + bp3.y * wv.y + bp3.z * wv.z + bp3.w * wv.w;
      if (i < 10) {
        int ktn2 = ktn + 64;
        bp0 = *(const float4*)(bptr0 + ktn2);
        bp1 = *(const float4*)(bptr1 + ktn2);
        bp2 = *(const float4*)(bptr2 + ktn2);
        bp3 = *(const float4*)(bptr3 + ktn2);
        if (!ok3) bp3 = (float4){0.f, 0.f, 0.f, 0.f};
      }
    }
    // compute on buf cur
#pragma unroll
    for (int h = 0; h < 2; ++h) {
      bf16x8 af[4], bfr[4];
#pragma unroll
      for (int m = 0; m < 4; ++m)
        af[m] = *(const bf16x8*)&As[cur * 2 + h][(wr * 64 + m * 16 + (l & 15)) * 32 + rd_off];
#pragma unroll
      for (int n = 0; n < 4; ++n)
        bfr[n] = *(const bf16x8*)&Bs[cur * 2 + h][(wc * 64 + n * 16 + (l & 15)) * 32 + rd_off];
#pragma unroll
      for (int m = 0; m < 4; ++m)
#pragma unroll
        for (int n = 0; n < 4; ++n)
          acc[m][n] = __builtin_amdgcn_mfma_f32_16x16x32_bf16(af[m], bfr[n], acc[m][n], 0, 0, 0);
    }
    __syncthreads();  // next buf staged + this buf's reads done
  }

  // finish w: 16-lane (c4) shfl reduce, then mask & publish
  wa0 += __shfl_xor(wa0, 1, 64); wa0 += __shfl_xor(wa0, 2, 64);
  wa0 += __shfl_xor(wa0, 4, 64); wa0 += __shfl_xor(wa0, 8, 64);
  wa1 += __shfl_xor(wa1, 1, 64); wa1 += __shfl_xor(wa1, 2, 64);
  wa1 += __shfl_xor(wa1, 4, 64); wa1 += __shfl_xor(wa1, 8, 64);
  wa2 += __shfl_xor(wa2, 1, 64); wa2 += __shfl_xor(wa2, 2, 64);
  wa2 += __shfl_xor(wa2, 4, 64); wa2 += __shfl_xor(wa2, 8, 64);
  wa3 += __shfl_xor(wa3, 1, 64); wa3 += __shfl_xor(wa3, 2, 64);
  wa3 += __shfl_xor(wa3, 4, 64); wa3 += __shfl_xor(wa3, 8, 64);
  if (c4 == 0) {
    const int* cm = cand_mask + (size_t)b * S_;
    w_lds[row_k0] = (cm[row_k0] != 0) ? wa0 : 0.f;
    w_lds[row_k1] = (cm[row_k1] != 0) ? wa1 : 0.f;
    w_lds[row_k2] = (cm[row_k2] != 0) ? wa2 : 0.f;
    w_lds[row_k3] = (ok3 && cm[ok3 ? row_k3 : 0] != 0) ? wa3 : 0.f;
  }
  __syncthreads();

  float rs[4][4];
#pragma unroll
  for (int m = 0; m < 4; ++m)
#pragma unroll
    for (int i = 0; i < 4; ++i) rs[m][i] = 0.f;

#pragma unroll
  for (int n = 0; n < 4; ++n) {
    float wcol = w_lds[wc * 64 + n * 16 + (l & 15)];
#pragma unroll
    for (int m = 0; m < 4; ++m)
#pragma unroll
      for (int i = 0; i < 4; ++i) {
        float p = 1.f / (1.f + __expf(-acc[m][n][i]));
        rs[m][i] += p * wcol;
      }
  }
#pragma unroll
  for (int m = 0; m < 4; ++m)
#pragma unroll
    for (int i = 0; i < 4; ++i) {
      float v = rs[m][i];
      v += __shfl_xor(v, 1, 64);
      v += __shfl_xor(v, 2, 64);
      v += __shfl_xor(v, 4, 64);
      v += __shfl_xor(v, 8, 64);
      rs[m][i] = v;
    }
  if ((l & 15) == 0) {
#pragma unroll
    for (int m = 0; m < 4; ++m)
#pragma unroll
      for (int i = 0; i < 4; ++i)
        xpart[wc][wr * 64 + m * 16 + (l >> 4) * 4 + i] = rs[m][i];
  }
  __syncthreads();
  if (tid < 256) {
    float xs = xpart[0][tid] + xpart[1][tid] + xpart[2][tid] + xpart[3][tid];
    int gm = ctx_mask[(size_t)b * 256 + tid];
    xbuf[(size_t)b * 256 + tid] = gm ? xs : 0.f;
  }
}

// ---------------- k_mlp: y[b] = (x[b]^T W1 + b1) W2 + b2 -------------------
__global__ __launch_bounds__(128) void k_mlp(const float* __restrict__ xbuf,
                                             const float* __restrict__ W1,
                                             const float* __restrict__ b1,
                                             const float* __restrict__ W2,
                                             const float* __restrict__ b2,
                                             float* __restrict__ out) {
  int b = blockIdx.x, t = threadIdx.x;
  __shared__ float xl[256];
  __shared__ float hl[128];
  xl[t]       = xbuf[(size_t)b * 256 + t];
  xl[t + 128] = xbuf[(size_t)b * 256 + 128 + t];
  __syncthreads();
  float acc = b1[t];
#pragma unroll 8
  for (int ll = 0; ll < 256; ++ll) acc += xl[ll] * W1[ll * H_ + t];
  hl[t] = acc;
  __syncthreads();
  if (t < 5) {
    float y = b2[t];
#pragma unroll 8
    for (int h = 0; h < H_; ++h) y += hl[h] * W2[h * 5 + t];
    out[(size_t)b * 5 + t] = y;
  }
}

extern "C" void kernel_launch(void* const* d_in, const int* in_sizes, int n_in,
                              void* d_out, int out_size, void* d_ws, size_t ws_size,
                              hipStream_t stream) {
  const float* ctx       = (const float*)d_in[0];
  const float* cand      = (const float*)d_in[1];
  const int*   ctx_mask  = (const int*)d_in[2];
  const int*   cand_mask = (const int*)d_in[3];
  const float* WK        = (const float*)d_in[4];
  const float* WQ        = (const float*)d_in[5];
  const float* WV        = (const float*)d_in[6];
  const float* W1        = (const float*)d_in[7];
  const float* b1        = (const float*)d_in[8];
  const float* W2        = (const float*)d_in[9];
  const float* b2        = (const float*)d_in[10];
  float* out = (float*)d_out;

  char* ws = (char*)d_ws;
  size_t off = 0;
  auto alloc = [&](size_t bytes) {
    void* p = ws + off;
    off += (bytes + 255) & ~(size_t)255;
    return p;
  };
  ushort* Mt   = (ushort*)alloc((size_t)D_ * D_ * 2);        // 1.18 MB
  ushort* wqb  = (ushort*)alloc((size_t)D_ * D_ * 2);        // 1.18 MB
  float*  xbuf = (float*) alloc((size_t)B_ * L_ * 4);        // 256 KB
  ushort* qm   = (ushort*)alloc((size_t)B_ * L_ * D_ * 2);   // 100.7 MB
  (void)ws_size; (void)in_sizes; (void)n_in; (void)out_size;

  k_wqb <<<D_ * D_ / 4 / 256,  256, 0, stream>>>(WQ, wqb);
  k_mtm <<<36,                 256, 0, stream>>>(WK, wqb, Mt);
  k_qm  <<<B_ * L_ / 128 * 6,  256, 0, stream>>>(ctx, Mt, qm);
  k_attn<<<B_,                1024, 0, stream>>>(qm, cand, cand_mask, ctx_mask, WV, xbuf);
  k_mlp <<<B_,                 128, 0, stream>>>(xbuf, W1, b1, W2, b2, out);
}

// Round 16
// 194.262 us; speedup vs baseline: 1.5076x; 1.2886x over previous
//
#include <hip/hip_runtime.h>
#include <hip/hip_bf16.h>
#include <stdint.h>

#define B_  256
#define L_  256
#define S_  253
#define D_  768
#define H_  128

typedef __bf16 bf16x8 __attribute__((ext_vector_type(8)));
typedef float  f32x4  __attribute__((ext_vector_type(4)));

__device__ __forceinline__ ushort f2bf(float f) {
  union { float f; uint32_t u; } v; v.f = f;
  uint32_t r = v.u + 0x7FFFu + ((v.u >> 16) & 1u);  // RNE
  return (ushort)(r >> 16);
}

__device__ __forceinline__ uint32_t cvtpk(float lo, float hi) {
  uint32_t r;
  asm("v_cvt_pk_bf16_f32 %0, %1, %2" : "=v"(r) : "v"(lo), "v"(hi));
  return r;
}

__device__ __forceinline__ void gload16(const void* g, void* l) {
  __builtin_amdgcn_global_load_lds((const __attribute__((address_space(1))) void*)g,
                                   (__attribute__((address_space(3))) void*)l,
                                   16, 0, 0);
}

// Bank swizzle (verified R5: read conflicts -> 0). LDS rows of 32 ushort =
// 4 slots of 16 B; stored slot s at row r holds global slot s ^ ((r>>1)&3).
#define SRC_OFF(l) ((((l) & 3) ^ (((l) >> 3) & 3)) * 8)
#define RD_OFF(l)  (((((l) >> 4) ^ (((l) >> 1) & 3))) * 8)
#define PANEL128 (128 * 32)
#define PANEL256 (256 * 32 + 32)

// ---------------- compaction micro-kernels (ctx_mask row sparsity ~50%) -----
__global__ __launch_bounds__(256) void k_cnt(const int* __restrict__ ctx_mask,
                                             int* __restrict__ cntbuf) {
  __shared__ int wsum[4];
  int b = blockIdx.x, tid = threadIdx.x;
  int m = ctx_mask[(size_t)b * 256 + tid] != 0;
  unsigned long long bal = __ballot(m);
  if ((tid & 63) == 0) wsum[tid >> 6] = __popcll(bal);
  __syncthreads();
  if (tid == 0) cntbuf[b] = wsum[0] + wsum[1] + wsum[2] + wsum[3];
}

__global__ __launch_bounds__(256) void k_scan(const int* __restrict__ cntbuf,
                                              int* __restrict__ start) {
  __shared__ int lds[256];
  int tid = threadIdx.x;
  lds[tid] = cntbuf[tid];
  __syncthreads();
  for (int off = 1; off < 256; off <<= 1) {
    int v = (tid >= off) ? lds[tid - off] : 0;
    __syncthreads();
    lds[tid] += v;
    __syncthreads();
  }
  start[tid + 1] = lds[tid];   // inclusive scan -> start[b+1]; start[256]=total
  if (tid == 0) start[0] = 0;
}

__global__ __launch_bounds__(256) void k_scatter(const int* __restrict__ ctx_mask,
                                                 const int* __restrict__ start,
                                                 int* __restrict__ rowidx,
                                                 int* __restrict__ rowl) {
  __shared__ int lds[256];
  int b = blockIdx.x, tid = threadIdx.x;
  int m = ctx_mask[(size_t)b * 256 + tid] != 0;
  lds[tid] = m;
  __syncthreads();
  for (int off = 1; off < 256; off <<= 1) {
    int v = (tid >= off) ? lds[tid - off] : 0;
    __syncthreads();
    lds[tid] += v;
    __syncthreads();
  }
  if (m) {
    int dst = start[b] + lds[tid] - 1;   // exclusive position
    rowidx[dst] = b * 256 + tid;
    rowl[dst]   = tid;
  }
}

// ---------------- k_wqb: WQ f32 -> bf16 row-copy ----------------------------
__global__ __launch_bounds__(256) void k_wqb(const float* __restrict__ WQ,
                                             ushort* __restrict__ wqb) {
  int i = blockIdx.x * 256 + threadIdx.x;   // 147456 float4s exactly
  float4 c = ((const float4*)WQ)[i];
  ushort4 o;
  o.x = f2bf(c.x); o.y = f2bf(c.y); o.z = f2bf(c.z); o.w = f2bf(c.w);
  ((ushort4*)wqb)[i] = o;
}

// ---------------- k_mtm: Mt[i][j] = scale * sum_t WK[i,t]*WQ[j,t] (MFMA) ----
__global__ __launch_bounds__(256) void k_mtm(const float* __restrict__ WK,
                                             const ushort* __restrict__ wqb,
                                             ushort* __restrict__ Mt) {
  const float scale = 0.03608439182435161f;  // 1/sqrt(768)
  __shared__ __align__(16) ushort As[2][PANEL128];
  __shared__ __align__(16) ushort Bs[2][PANEL128];
  int bm = blockIdx.x / 6, bn = blockIdx.x % 6;
  int row0 = bm * 128, col0 = bn * 128;
  int tid = threadIdx.x;
  int w = tid >> 6, l = tid & 63;
  int wr = w >> 1, wc = w & 1;
  int src_off = SRC_OFF(l);
  int rd_off  = RD_OFF(l);

  int rt = tid >> 4;
  int c4 = tid & 15;
  int h_thr = c4 >> 3;
  int cw = c4 & 7;
  const float* athr = WK + (size_t)(row0 + rt) * D_ + 4 * c4;
  int aw_base = rt * 64 + ((cw >> 1) ^ ((rt >> 1) & 3)) * 16 + (cw & 1) * 8;
  char* aw_ptr = (char*)&As[h_thr][0] + aw_base;

  f32x4 acc[4][4];
#pragma unroll
  for (int m = 0; m < 4; ++m)
#pragma unroll
    for (int n = 0; n < 4; ++n) acc[m][n] = (f32x4){0.f, 0.f, 0.f, 0.f};

  float4 ap0, ap1, ap2, ap3, ap4, ap5, ap6, ap7;
  ap0 = *(const float4*)(athr + 0 * 12288);
  ap1 = *(const float4*)(athr + 1 * 12288);
  ap2 = *(const float4*)(athr + 2 * 12288);
  ap3 = *(const float4*)(athr + 3 * 12288);
  ap4 = *(const float4*)(athr + 4 * 12288);
  ap5 = *(const float4*)(athr + 5 * 12288);
  ap6 = *(const float4*)(athr + 6 * 12288);
  ap7 = *(const float4*)(athr + 7 * 12288);

  for (int i = 0; i < 12; ++i) {
    int kt = i * 64;
    if (i) __syncthreads();
    {
      uint2 d;
      d.x = cvtpk(ap0.x, ap0.y); d.y = cvtpk(ap0.z, ap0.w);
      *(uint2*)(aw_ptr + 0 * 1024) = d;
      d.x = cvtpk(ap1.x, ap1.y); d.y = cvtpk(ap1.z, ap1.w);
      *(uint2*)(aw_ptr + 1 * 1024) = d;
      d.x = cvtpk(ap2.x, ap2.y); d.y = cvtpk(ap2.z, ap2.w);
      *(uint2*)(aw_ptr + 2 * 1024) = d;
      d.x = cvtpk(ap3.x, ap3.y); d.y = cvtpk(ap3.z, ap3.w);
      *(uint2*)(aw_ptr + 3 * 1024) = d;
      d.x = cvtpk(ap4.x, ap4.y); d.y = cvtpk(ap4.z, ap4.w);
      *(uint2*)(aw_ptr + 4 * 1024) = d;
      d.x = cvtpk(ap5.x, ap5.y); d.y = cvtpk(ap5.z, ap5.w);
      *(uint2*)(aw_ptr + 5 * 1024) = d;
      d.x = cvtpk(ap6.x, ap6.y); d.y = cvtpk(ap6.z, ap6.w);
      *(uint2*)(aw_ptr + 6 * 1024) = d;
      d.x = cvtpk(ap7.x, ap7.y); d.y = cvtpk(ap7.z, ap7.w);
      *(uint2*)(aw_ptr + 7 * 1024) = d;
    }
#pragma unroll
    for (int hh = 0; hh < 2; ++hh)
#pragma unroll
      for (int g = 0; g < 2; ++g) {
        int grp = w * 2 + g;
        int grow = grp * 16 + (l >> 2);
        const ushort* bsrc = wqb + (size_t)(col0 + grow) * D_ + kt + hh * 32 + src_off;
        gload16(bsrc, (char*)Bs[hh] + grp * 1024);
      }
    {
      int ktn = (i < 11) ? kt + 64 : kt;
      const float* an = athr + ktn;
      ap0 = *(const float4*)(an + 0 * 12288);
      ap1 = *(const float4*)(an + 1 * 12288);
      ap2 = *(const float4*)(an + 2 * 12288);
      ap3 = *(const float4*)(an + 3 * 12288);
      ap4 = *(const float4*)(an + 4 * 12288);
      ap5 = *(const float4*)(an + 5 * 12288);
      ap6 = *(const float4*)(an + 6 * 12288);
      ap7 = *(const float4*)(an + 7 * 12288);
    }
    __syncthreads();

#pragma unroll
    for (int hh = 0; hh < 2; ++hh) {
      bf16x8 af[4], bfr[4];
#pragma unroll
      for (int m = 0; m < 4; ++m)
        af[m] = *(const bf16x8*)&As[hh][(wr * 64 + m * 16 + (l & 15)) * 32 + rd_off];
#pragma unroll
      for (int n = 0; n < 4; ++n)
        bfr[n] = *(const bf16x8*)&Bs[hh][(wc * 64 + n * 16 + (l & 15)) * 32 + rd_off];
#pragma unroll
      for (int m = 0; m < 4; ++m)
#pragma unroll
        for (int n = 0; n < 4; ++n)
          acc[m][n] = __builtin_amdgcn_mfma_f32_16x16x32_bf16(af[m], bfr[n], acc[m][n], 0, 0, 0);
    }
  }

  int rbase = row0 + wr * 64;
  int cbase = col0 + wc * 64;
#pragma unroll
  for (int m = 0; m < 4; ++m)
#pragma unroll
    for (int n = 0; n < 4; ++n)
#pragma unroll
      for (int i = 0; i < 4; ++i) {
        int rr = rbase + m * 16 + (l >> 4) * 4 + i;
        int cc = cbase + n * 16 + (l & 15);
        Mt[(size_t)rr * D_ + cc] = f2bf(acc[m][n][i] * scale);
      }
}

// ---------------- k_qm: qm_c[r] = ctx[rowidx[r]] . Mt (bf16, COMPACT) -------
// R11/R13-proven body; only row addressing changed: compact rows via rowidx,
// early-exit blocks past total. bm map (idx/6)*8+xcd keeps active bm-prefix
// XCD-balanced while 6 bn-blocks per bm stay XCD-adjacent.
__global__ __launch_bounds__(256) void k_qm(const float* __restrict__ ctx,
                                            const ushort* __restrict__ Mt,
                                            const int* __restrict__ rowidx,
                                            const int* __restrict__ start,
                                            ushort* __restrict__ qm) {
  __shared__ __align__(16) ushort As[2][PANEL128];
  __shared__ __align__(16) ushort Bs[2][PANEL128];
  int total = start[256];
  int bid0 = blockIdx.x;              // 0..3071
  int xcd = bid0 & 7;
  int idx = bid0 >> 3;                // 0..383
  int bm = (idx / 6) * 8 + xcd;       // 0..511 bijective, prefix XCD-balanced
  int bn = idx % 6;
  int row0 = bm * 128, col0 = bn * 128;
  if (row0 >= total) return;          // block-uniform early exit
  int tid = threadIdx.x;
  int w = tid >> 6, l = tid & 63;
  int wr = w >> 1, wc = w & 1;
  int src_off = SRC_OFF(l);
  int rd_off  = RD_OFF(l);

  int rt = tid >> 4;
  int c4 = tid & 15;
  int h_thr = c4 >> 3;
  int cw = c4 & 7;
  int aw_base = rt * 64 + ((cw >> 1) ^ ((rt >> 1) & 3)) * 16 + (cw & 1) * 8;
  char* aw_ptr = (char*)&As[h_thr][0] + aw_base;

  // compact -> original row pointers (clamped; dup rows benign, stores guarded)
  const float *apt0, *apt1, *apt2, *apt3, *apt4, *apt5, *apt6, *apt7;
  {
    int t1 = total - 1;
    int rc;
    rc = row0 + rt +   0; rc = rc < t1 ? rc : t1;
    apt0 = ctx + (size_t)rowidx[rc] * D_ + 4 * c4;
    rc = row0 + rt +  16; rc = rc < t1 ? rc : t1;
    apt1 = ctx + (size_t)rowidx[rc] * D_ + 4 * c4;
    rc = row0 + rt +  32; rc = rc < t1 ? rc : t1;
    apt2 = ctx + (size_t)rowidx[rc] * D_ + 4 * c4;
    rc = row0 + rt +  48; rc = rc < t1 ? rc : t1;
    apt3 = ctx + (size_t)rowidx[rc] * D_ + 4 * c4;
    rc = row0 + rt +  64; rc = rc < t1 ? rc : t1;
    apt4 = ctx + (size_t)rowidx[rc] * D_ + 4 * c4;
    rc = row0 + rt +  80; rc = rc < t1 ? rc : t1;
    apt5 = ctx + (size_t)rowidx[rc] * D_ + 4 * c4;
    rc = row0 + rt +  96; rc = rc < t1 ? rc : t1;
    apt6 = ctx + (size_t)rowidx[rc] * D_ + 4 * c4;
    rc = row0 + rt + 112; rc = rc < t1 ? rc : t1;
    apt7 = ctx + (size_t)rowidx[rc] * D_ + 4 * c4;
  }

  f32x4 acc[4][4];
#pragma unroll
  for (int m = 0; m < 4; ++m)
#pragma unroll
    for (int n = 0; n < 4; ++n) acc[m][n] = (f32x4){0.f, 0.f, 0.f, 0.f};

  float4 ap0, ap1, ap2, ap3, ap4, ap5, ap6, ap7;
  ap0 = *(const float4*)(apt0);
  ap1 = *(const float4*)(apt1);
  ap2 = *(const float4*)(apt2);
  ap3 = *(const float4*)(apt3);
  ap4 = *(const float4*)(apt4);
  ap5 = *(const float4*)(apt5);
  ap6 = *(const float4*)(apt6);
  ap7 = *(const float4*)(apt7);

  for (int i = 0; i < 12; ++i) {
    int kt = i * 64;
    if (i) __syncthreads();
    {
      uint2 d;
      d.x = cvtpk(ap0.x, ap0.y); d.y = cvtpk(ap0.z, ap0.w);
      *(uint2*)(aw_ptr + 0 * 1024) = d;
      d.x = cvtpk(ap1.x, ap1.y); d.y = cvtpk(ap1.z, ap1.w);
      *(uint2*)(aw_ptr + 1 * 1024) = d;
      d.x = cvtpk(ap2.x, ap2.y); d.y = cvtpk(ap2.z, ap2.w);
      *(uint2*)(aw_ptr + 2 * 1024) = d;
      d.x = cvtpk(ap3.x, ap3.y); d.y = cvtpk(ap3.z, ap3.w);
      *(uint2*)(aw_ptr + 3 * 1024) = d;
      d.x = cvtpk(ap4.x, ap4.y); d.y = cvtpk(ap4.z, ap4.w);
      *(uint2*)(aw_ptr + 4 * 1024) = d;
      d.x = cvtpk(ap5.x, ap5.y); d.y = cvtpk(ap5.z, ap5.w);
      *(uint2*)(aw_ptr + 5 * 1024) = d;
      d.x = cvtpk(ap6.x, ap6.y); d.y = cvtpk(ap6.z, ap6.w);
      *(uint2*)(aw_ptr + 6 * 1024) = d;
      d.x = cvtpk(ap7.x, ap7.y); d.y = cvtpk(ap7.z, ap7.w);
      *(uint2*)(aw_ptr + 7 * 1024) = d;
    }
#pragma unroll
    for (int hh = 0; hh < 2; ++hh)
#pragma unroll
      for (int g = 0; g < 2; ++g) {
        int grp = w * 2 + g;
        int grow = grp * 16 + (l >> 2);
        const ushort* bsrc = Mt + (size_t)(col0 + grow) * D_ + kt + hh * 32 + src_off;
        gload16(bsrc, (char*)Bs[hh] + grp * 1024);
      }
    {
      int ktn = (i < 11) ? kt + 64 : kt;
      ap0 = *(const float4*)(apt0 + ktn);
      ap1 = *(const float4*)(apt1 + ktn);
      ap2 = *(const float4*)(apt2 + ktn);
      ap3 = *(const float4*)(apt3 + ktn);
      ap4 = *(const float4*)(apt4 + ktn);
      ap5 = *(const float4*)(apt5 + ktn);
      ap6 = *(const float4*)(apt6 + ktn);
      ap7 = *(const float4*)(apt7 + ktn);
    }
    __syncthreads();

#pragma unroll
    for (int hh = 0; hh < 2; ++hh) {
      bf16x8 af[4], bfr[4];
#pragma unroll
      for (int m = 0; m < 4; ++m)
        af[m] = *(const bf16x8*)&As[hh][(wr * 64 + m * 16 + (l & 15)) * 32 + rd_off];
#pragma unroll
      for (int n = 0; n < 4; ++n)
        bfr[n] = *(const bf16x8*)&Bs[hh][(wc * 64 + n * 16 + (l & 15)) * 32 + rd_off];
#pragma unroll
      for (int m = 0; m < 4; ++m)
#pragma unroll
        for (int n = 0; n < 4; ++n)
          acc[m][n] = __builtin_amdgcn_mfma_f32_16x16x32_bf16(af[m], bfr[n], acc[m][n], 0, 0, 0);
    }
  }

  int rbase = row0 + wr * 64;
  int cbase = col0 + wc * 64;
#pragma unroll
  for (int m = 0; m < 4; ++m)
#pragma unroll
    for (int n = 0; n < 4; ++n)
#pragma unroll
      for (int i = 0; i < 4; ++i) {
        int rr = rbase + m * 16 + (l >> 4) * 4 + i;
        int cc = cbase + n * 16 + (l & 15);
        if (rr < total) qm[(size_t)rr * D_ + cc] = f2bf(acc[m][n][i]);
      }
}

// ---------------- k_attn: full fusion, dbuf (R13) + compact-qm rows ---------
// A rows = qm_c[start[b] .. start[b]+255] (clamped; rows >= cnt are garbage,
// discarded by the rowl scatter). Inactive x slots zeroed explicitly.
__global__ __launch_bounds__(1024) void k_attn(const ushort* __restrict__ qm,
                                               const float* __restrict__ cand,
                                               const int* __restrict__ cand_mask,
                                               const int* __restrict__ start,
                                               const int* __restrict__ rowl,
                                               const float* __restrict__ WV,
                                               float* __restrict__ xbuf) {
  __shared__ __align__(16) ushort As[4][PANEL256];   // 65.8 KB
  __shared__ __align__(16) ushort Bs[4][PANEL256];   // 65.8 KB
  __shared__ float wv_lds[D_];
  __shared__ float w_lds[256];
  __shared__ float xpart[4][256];
  int b = blockIdx.x;
  int st = start[b];
  int cnt = start[b + 1] - st;
  int total = start[256];
  int tid = threadIdx.x;
  int w = tid >> 6, l = tid & 63;
  int wr = w >> 2, wc = w & 3;             // 4x4 wave grid
  int src_off = SRC_OFF(l);
  int rd_off  = RD_OFF(l);

  if (tid < D_) wv_lds[tid] = WV[tid];

  int rt = tid >> 4;
  int c4 = tid & 15;
  int h_thr = c4 >> 3;
  int cw = c4 & 7;
  int row_k0 = rt, row_k1 = rt + 64, row_k2 = rt + 128, row_k3 = rt + 192;
  int ok3 = row_k3 < S_;                   // only k=3 can be out of range
  const float* bptr0 = cand + ((size_t)b * S_ + row_k0) * D_ + 4 * c4;
  const float* bptr1 = cand + ((size_t)b * S_ + row_k1) * D_ + 4 * c4;
  const float* bptr2 = cand + ((size_t)b * S_ + row_k2) * D_ + 4 * c4;
  const float* bptr3 = cand + ((size_t)b * S_ + (ok3 ? row_k3 : S_ - 1)) * D_ + 4 * c4;
  int bw_base = rt * 64 + ((cw >> 1) ^ ((rt >> 1) & 3)) * 16 + (cw & 1) * 8;

  // A-row (compact qm) for this wave's staging lane, clamped to total-1
  int arow_l = st + w * 16 + (l >> 2);
  arow_l = arow_l < total ? arow_l : total - 1;
  const ushort* aptr = qm + (size_t)arow_l * D_ + src_off;

  f32x4 acc[4][4];
#pragma unroll
  for (int m = 0; m < 4; ++m)
#pragma unroll
    for (int n = 0; n < 4; ++n) acc[m][n] = (f32x4){0.f, 0.f, 0.f, 0.f};
  float wa0 = 0.f, wa1 = 0.f, wa2 = 0.f, wa3 = 0.f;

  __syncthreads();  // wv_lds ready

  float4 bp0 = *(const float4*)(bptr0);
  float4 bp1 = *(const float4*)(bptr1);
  float4 bp2 = *(const float4*)(bptr2);
  float4 bp3 = *(const float4*)(bptr3);
  if (!ok3) bp3 = (float4){0.f, 0.f, 0.f, 0.f};

  // ---- prologue: stage kt=0 into buf 0, wacc(kt0), prefetch kt=64 ----
  {
    char* bw_ptr = (char*)&Bs[h_thr][0] + bw_base;
    uint2 d;
    d.x = cvtpk(bp0.x, bp0.y); d.y = cvtpk(bp0.z, bp0.w);
    *(uint2*)(bw_ptr + 0 * 4096) = d;
    d.x = cvtpk(bp1.x, bp1.y); d.y = cvtpk(bp1.z, bp1.w);
    *(uint2*)(bw_ptr + 1 * 4096) = d;
    d.x = cvtpk(bp2.x, bp2.y); d.y = cvtpk(bp2.z, bp2.w);
    *(uint2*)(bw_ptr + 2 * 4096) = d;
    d.x = cvtpk(bp3.x, bp3.y); d.y = cvtpk(bp3.z, bp3.w);
    *(uint2*)(bw_ptr + 3 * 4096) = d;
#pragma unroll
    for (int h = 0; h < 2; ++h)
      gload16(aptr + h * 32, (char*)As[h] + w * 1024);
    float4 wv = *(const float4*)&wv_lds[4 * c4];
    wa0 += bp0.x * wv.x + bp0.y * wv.y + bp0.z * wv.z + bp0.w * wv.w;
    wa1 += bp1.x * wv.x + bp1.y * wv.y + bp1.z * wv.z + bp1.w * wv.w;
    wa2 += bp2.x * wv.x + bp2.y * wv.y + bp2.z * wv.z + bp2.w * wv.w;
    wa3 += bp3.x * wv.x + bp3.y * wv.y + bp3.z * wv.z + bp3.w * wv.w;
    bp0 = *(const float4*)(bptr0 + 64);
    bp1 = *(const float4*)(bptr1 + 64);
    bp2 = *(const float4*)(bptr2 + 64);
    bp3 = *(const float4*)(bptr3 + 64);
    if (!ok3) bp3 = (float4){0.f, 0.f, 0.f, 0.f};
  }
  __syncthreads();  // buf0 ready

  for (int i = 0; i < 12; ++i) {
    int cur = i & 1, nxt = cur ^ 1;
    if (i < 11) {
      int ktn = (i + 1) * 64;  // bp holds this kt's data
      char* bw_ptr = (char*)&Bs[nxt * 2 + h_thr][0] + bw_base;
      uint2 d;
      d.x = cvtpk(bp0.x, bp0.y); d.y = cvtpk(bp0.z, bp0.w);
      *(uint2*)(bw_ptr + 0 * 4096) = d;
      d.x = cvtpk(bp1.x, bp1.y); d.y = cvtpk(bp1.z, bp1.w);
      *(uint2*)(bw_ptr + 1 * 4096) = d;
      d.x = cvtpk(bp2.x, bp2.y); d.y = cvtpk(bp2.z, bp2.w);
      *(uint2*)(bw_ptr + 2 * 4096) = d;
      d.x = cvtpk(bp3.x, bp3.y); d.y = cvtpk(bp3.z, bp3.w);
      *(uint2*)(bw_ptr + 3 * 4096) = d;
#pragma unroll
      for (int h = 0; h < 2; ++h)
        gload16(aptr + ktn + h * 32, (char*)As[nxt * 2 + h] + w * 1024);
      float4 wv = *(const float4*)&wv_lds[ktn + 4 * c4];
      wa0 += bp0.x * wv.x + bp0.y * wv.y + bp0.z * wv.z + bp0.w * wv.w;
      wa1 += bp1.x * wv.x + bp1.y * wv.y + bp1.z * wv.z + bp1.w * wv.w;
      wa2 += bp2.x * wv.x + bp2.y * wv.y + bp2.z * wv.z + bp2.w * wv.w;
      wa3 += bp3.x * wv.x + bp3.y * wv.y + bp3.z * wv.z + bp3.w * wv.w;
      if (i < 10) {
        int ktn2 = ktn + 64;
        bp0 = *(const float4*)(bptr0 + ktn2);
        bp1 = *(const float4*)(bptr1 + ktn2);
        bp2 = *(const float4*)(bptr2 + ktn2);
        bp3 = *(const float4*)(bptr3 + ktn2);
        if (!ok3) bp3 = (float4){0.f, 0.f, 0.f, 0.f};
      }
    }
    // compute on buf cur
#pragma unroll
    for (int h = 0; h < 2; ++h) {
      bf16x8 af[4], bfr[4];
#pragma unroll
      for (int m = 0; m < 4; ++m)
        af[m] = *(const bf16x8*)&As[cur * 2 + h][(wr * 64 + m * 16 + (l & 15)) * 32 + rd_off];
#pragma unroll
      for (int n = 0; n < 4; ++n)
        bfr[n] = *(const bf16x8*)&Bs[cur * 2 + h][(wc * 64 + n * 16 + (l & 15)) * 32 + rd_off];
#pragma unroll
      for (int m = 0; m < 4; ++m)
#pragma unroll
        for (int n = 0; n < 4; ++n)
          acc[m][n] = __builtin_amdgcn_mfma_f32_16x16x32_bf16(af[m], bfr[n], acc[m][n], 0, 0, 0);
    }
    __syncthreads();  // next buf staged + this buf's reads done
  }

  // finish w: 16-lane (c4) shfl reduce, then mask & publish
  wa0 += __shfl_xor(wa0, 1, 64); wa0 += __shfl_xor(wa0, 2, 64);
  wa0 += __shfl_xor(wa0, 4, 64); wa0 += __shfl_xor(wa0, 8, 64);
  wa1 += __shfl_xor(wa1, 1, 64); wa1 += __shfl_xor(wa1, 2, 64);
  wa1 += __shfl_xor(wa1, 4, 64); wa1 += __shfl_xor(wa1, 8, 64);
  wa2 += __shfl_xor(wa2, 1, 64); wa2 += __shfl_xor(wa2, 2, 64);
  wa2 += __shfl_xor(wa2, 4, 64); wa2 += __shfl_xor(wa2, 8, 64);
  wa3 += __shfl_xor(wa3, 1, 64); wa3 += __shfl_xor(wa3, 2, 64);
  wa3 += __shfl_xor(wa3, 4, 64); wa3 += __shfl_xor(wa3, 8, 64);
  if (c4 == 0) {
    const int* cm = cand_mask + (size_t)b * S_;
    w_lds[row_k0] = (cm[row_k0] != 0) ? wa0 : 0.f;
    w_lds[row_k1] = (cm[row_k1] != 0) ? wa1 : 0.f;
    w_lds[row_k2] = (cm[row_k2] != 0) ? wa2 : 0.f;
    w_lds[row_k3] = (ok3 && cm[ok3 ? row_k3 : 0] != 0) ? wa3 : 0.f;
  }
  __syncthreads();

  float rs[4][4];
#pragma unroll
  for (int m = 0; m < 4; ++m)
#pragma unroll
    for (int i = 0; i < 4; ++i) rs[m][i] = 0.f;

#pragma unroll
  for (int n = 0; n < 4; ++n) {
    float wcol = w_lds[wc * 64 + n * 16 + (l & 15)];
#pragma unroll
    for (int m = 0; m < 4; ++m)
#pragma unroll
      for (int i = 0; i < 4; ++i) {
        float p = 1.f / (1.f + __expf(-acc[m][n][i]));
        rs[m][i] += p * wcol;
      }
  }
#pragma unroll
  for (int m = 0; m < 4; ++m)
#pragma unroll
    for (int i = 0; i < 4; ++i) {
      float v = rs[m][i];
      v += __shfl_xor(v, 1, 64);
      v += __shfl_xor(v, 2, 64);
      v += __shfl_xor(v, 4, 64);
      v += __shfl_xor(v, 8, 64);
      rs[m][i] = v;
    }
  if ((l & 15) == 0) {
#pragma unroll
    for (int m = 0; m < 4; ++m)
#pragma unroll
      for (int i = 0; i < 4; ++i)
        xpart[wc][wr * 64 + m * 16 + (l >> 4) * 4 + i] = rs[m][i];
  }
  __syncthreads();
  if (tid < 256) {
    float xs = xpart[0][tid] + xpart[1][tid] + xpart[2][tid] + xpart[3][tid];
    xbuf[(size_t)b * 256 + tid] = 0.f;      // zero all (covers inactive rows)
    __syncthreads();                        // order zeros before scatter
    if (tid < cnt)
      xbuf[(size_t)b * 256 + rowl[st + tid]] = xs;  // scatter actives
  } else {
    __syncthreads();                        // match barrier
  }
}

// ---------------- k_mlp: y[b] = (x[b]^T W1 + b1) W2 + b2 -------------------
__global__ __launch_bounds__(128) void k_mlp(const float* __restrict__ xbuf,
                                             const float* __restrict__ W1,
                                             const float* __restrict__ b1,
                                             const float* __restrict__ W2,
                                             const float* __restrict__ b2,
                                             float* __restrict__ out) {
  int b = blockIdx.x, t = threadIdx.x;
  __shared__ float xl[256];
  __shared__ float hl[128];
  xl[t]       = xbuf[(size_t)b * 256 + t];
  xl[t + 128] = xbuf[(size_t)b * 256 + 128 + t];
  __syncthreads();
  float acc = b1[t];
#pragma unroll 8
  for (int ll = 0; ll < 256; ++ll) acc += xl[ll] * W1[ll * H_ + t];
  hl[t] = acc;
  __syncthreads();
  if (t < 5) {
    float y = b2[t];
#pragma unroll 8
    for (int h = 0; h < H_; ++h) y += hl[h] * W2[h * 5 + t];
    out[(size_t)b * 5 + t] = y;
  }
}

extern "C" void kernel_launch(void* const* d_in, const int* in_sizes, int n_in,
                              void* d_out, int out_size, void* d_ws, size_t ws_size,
                              hipStream_t stream) {
  const float* ctx       = (const float*)d_in[0];
  const float* cand      = (const float*)d_in[1];
  const int*   ctx_mask  = (const int*)d_in[2];
  const int*   cand_mask = (const int*)d_in[3];
  const float* WK        = (const float*)d_in[4];
  const float* WQ        = (const float*)d_in[5];
  const float* WV        = (const float*)d_in[6];
  const float* W1        = (const float*)d_in[7];
  const float* b1        = (const float*)d_in[8];
  const float* W2        = (const float*)d_in[9];
  const float* b2        = (const float*)d_in[10];
  float* out = (float*)d_out;

  char* ws = (char*)d_ws;
  size_t off = 0;
  auto alloc = [&](size_t bytes) {
    void* p = ws + off;
    off += (bytes + 255) & ~(size_t)255;
    return p;
  };
  ushort* Mt     = (ushort*)alloc((size_t)D_ * D_ * 2);        // 1.18 MB
  ushort* wqb    = (ushort*)alloc((size_t)D_ * D_ * 2);        // 1.18 MB
  float*  xbuf   = (float*) alloc((size_t)B_ * L_ * 4);        // 256 KB
  int*    cntbuf = (int*)   alloc(256 * 4);
  int*    startb = (int*)   alloc(257 * 4);
  int*    rowidx = (int*)   alloc((size_t)B_ * L_ * 4);        // 256 KB
  int*    rowlb  = (int*)   alloc((size_t)B_ * L_ * 4);        // 256 KB
  ushort* qm     = (ushort*)alloc((size_t)B_ * L_ * D_ * 2);   // 100.7 MB
  (void)ws_size; (void)in_sizes; (void)n_in; (void)out_size;

  k_cnt    <<<B_,                256, 0, stream>>>(ctx_mask, cntbuf);
  k_scan   <<<1,                 256, 0, stream>>>(cntbuf, startb);
  k_scatter<<<B_,                256, 0, stream>>>(ctx_mask, startb, rowidx, rowlb);
  k_wqb    <<<D_ * D_ / 4 / 256, 256, 0, stream>>>(WQ, wqb);
  k_mtm    <<<36,                256, 0, stream>>>(WK, wqb, Mt);
  k_qm     <<<B_ * L_ / 128 * 6, 256, 0, stream>>>(ctx, Mt, rowidx, startb, qm);
  k_attn   <<<B_,               1024, 0, stream>>>(qm, cand, cand_mask, startb, rowlb, WV, xbuf);
  k_mlp    <<<B_,                128, 0, stream>>>(xbuf, W1, b1, W2, b2, out);
}